// Round 7
// baseline (367.041 us; speedup 1.0000x reference)
//
#include <hip/hip_runtime.h>
#include <math.h>

typedef _Float16 h16;
typedef h16  h16x8 __attribute__((ext_vector_type(8)));
typedef h16  h16x4 __attribute__((ext_vector_type(4)));
typedef float f32x4 __attribute__((ext_vector_type(4)));

// ---------------- workspace layout (bytes) ----------------
#define MH_OFF   ((size_t)0)
#define ML_OFF   (MH_OFF + 16777216)
#define UHT_OFF  (ML_OFF + 16777216)
#define ULT_OFF  (UHT_OFF + 262144)
#define RMA_OFF  (ULT_OFF + 262144)
#define RMH_OFF  (RMA_OFF + 262144)
#define PCM_OFF  (RMH_OFF + 262144)
#define M0_OFF   (PCM_OFF + 4194304)

__device__ __forceinline__ float nonsat(float x) {
    float y = x;
#pragma unroll
    for (int i = 0; i < 24; ++i) {
        float y2 = y * y;
        y = fmaf(0.66666667f * y, y2, x) / (y2 + 1.0f);
    }
    return y;
}

__device__ __forceinline__ int fkey(float f) {
    const int i = __float_as_int(f);
    return (i >= 0) ? i : (i ^ 0x7fffffff);
}
__device__ __forceinline__ float funkey(int k) {
    return __int_as_float((k >= 0) ? k : (k ^ 0x7fffffff));
}

// ---------------------------------------------------------------------------
// k_prep: fp16 hi/lo split of virtual M (x2 zero-padded) and of U^T*4.
// ---------------------------------------------------------------------------
__global__ void k_prep(const float* __restrict__ x1, const float* __restrict__ x2,
                       const float* __restrict__ U, h16* __restrict__ MH,
                       h16* __restrict__ ML, h16* __restrict__ UHt,
                       h16* __restrict__ ULt, int* __restrict__ m0key,
                       float* __restrict__ out) {
    const int gid = blockIdx.x * 256 + threadIdx.x;
    if (blockIdx.x < 8192) {
        const int g  = gid;              // (b, j, d4): 32*1024*64 groups
        const int d4 = (g & 63) * 4;
        const int j  = (g >> 6) & 1023;
        const int b  = g >> 16;
        float v[4];
        if (j < 512) {
            const float4 p = *(const float4*)(x1 + ((size_t)(b * 512 + j) * 256 + d4));
            v[0] = p.x; v[1] = p.y; v[2] = p.z; v[3] = p.w;
        } else if (d4 < 192) {
            const float4 p = *(const float4*)(x2 +
                (size_t)(b * 512 + (j - 512)) * 192 + d4);
            v[0] = p.x; v[1] = p.y; v[2] = p.z; v[3] = p.w;
        } else {
            v[0] = v[1] = v[2] = v[3] = 0.0f;
        }
        h16x4 hh, ll;
#pragma unroll
        for (int k = 0; k < 4; ++k) {
            const h16 hi = (h16)v[k];
            hh[k] = hi;
            ll[k] = (h16)(v[k] - (float)hi);
        }
        const size_t o = (size_t)g * 4;
        *(h16x4*)&MH[o] = hh;
        *(h16x4*)&ML[o] = ll;
    } else if (blockIdx.x < 8320) {
        const int g  = gid - 8192 * 256; // U^T: 2*256*64 groups
        const int c4 = (g & 63) * 4;
        const int d  = (g >> 6) & 255;
        const int h  = g >> 14;
        h16x4 hh, ll;
#pragma unroll
        for (int k = 0; k < 4; ++k) {
            const float v = U[((size_t)h * 256 + c4 + k) * 256 + d] * 4.0f;
            const h16 hi = (h16)v;
            hh[k] = hi;
            ll[k] = (h16)(v - (float)hi);
        }
        const size_t o = ((size_t)h * 256 + d) * 256 + c4;
        *(h16x4*)&UHt[o] = hh;
        *(h16x4*)&ULt[o] = ll;
    } else {
        const int z = gid - 8320 * 256;
        out[z] = 0.0f;
        if (z == 0) *m0key = 0x7fffffff;
    }
}

// ---------------------------------------------------------------------------
// k_main (R17): counted-vmcnt pipeline (T3+T4). R6 post-mortem: T2 swizzle
// cut bank conflicts 3x with ZERO time delta — the binder is the 2-phase
// drain: __syncthreads' implicit vmcnt(0) drained the just-issued prefetch
// every step (m233: that chain is ~72% of a 2-phase loop). New structure:
//  * sB = 4 single-kc buffers (16 KB each: [128 j][32 d] x H/L planes),
//    depth-3 prefetch: stage(u+3) issued AFTER the top-of-step barrier
//    (target buf was being read until that barrier), awaited 3 steps later.
//  * per-step sync: s_waitcnt vmcnt(4|2|0 tail) + lgkmcnt(0) + raw s_barrier
//    — in-flight loads span barriers (m201 pattern; per-wave vmcnt + shared
//    barrier => all waves' stage(u) retired before any wave reads buf u).
//  * 64 steps of 12 MFMA/wave (same total MFMA; smaller, cheaper phases).
//  * scm publish gets its own raw barrier at jt-end (no vmcnt drain).
// Per-element MFMA order (kc-outer; HH,LH,HL) unchanged -> bitwise-identical.
// LDS: sP 64K + sB 64K + red 4.1K + scm 4K = 136 KB, 1 block/CU, 8 waves.
// ---------------------------------------------------------------------------
__device__ __forceinline__ void stage_b(const h16* __restrict__ MH,
                                        const h16* __restrict__ ML,
                                        h16* __restrict__ sBf, int b, int jts,
                                        int u, int t) {
    const int jt    = jts + (u >> 5);
    const int jtile = (u >> 3) & 3;
    const int kc    = u & 7;
    const int jrow0 = jt * 512 + jtile * 128;
    // landing slot: row = t>>2, 16B-chunk slot = t&3 (linear, wave-contiguous);
    // logical chunk placed there: c = (t&3) ^ ((row>>1)&3) (T2 involution).
    const int c = (t & 3) ^ ((t >> 3) & 3);
    const size_t src = (size_t)(b * 1024 + jrow0 + (t >> 2)) * 256 + kc * 32 + c * 8;
    h16* dH = sBf + (size_t)(u & 3) * 8192 + t * 8;
    h16* dL = sBf + (size_t)(u & 3) * 8192 + 4096 + t * 8;
    __builtin_amdgcn_global_load_lds(
        (const __attribute__((address_space(1))) void*)(MH + src),
        (__attribute__((address_space(3))) void*)dH, 16, 0, 0);
    __builtin_amdgcn_global_load_lds(
        (const __attribute__((address_space(1))) void*)(ML + src),
        (__attribute__((address_space(3))) void*)dL, 16, 0, 0);
}

__global__ __launch_bounds__(512, 2)
void k_main(const h16* __restrict__ MH, const h16* __restrict__ ML,
            const h16* __restrict__ UHt, const h16* __restrict__ ULt,
            float* __restrict__ rmax_all, float* __restrict__ rmax_hi,
            float* __restrict__ pcm, int* __restrict__ m0key) {
    __shared__ __align__(16) h16 sP[2][64 * 256];   // P hi/lo, swizzled, 64 KB
    __shared__ __align__(16) h16 sB[4 * 8192];      // 4 bufs x (H+L) x 8KB, 64 KB
    __shared__ float red[1024 + 8];
    __shared__ float scm[2][512];

    const int n    = blockIdx.x;       // 1024
    const int x    = n & 7;            // XCD-affine swizzle
    const int s    = n >> 3;
    const int b    = x + 8 * (s >> 5);
    const int h    = (s >> 4) & 1;
    const int rblk = s & 15;
    const int hb   = h * 32 + b;
    const int r0   = rblk * 64;
    const int t    = threadIdx.x;
    const int w    = t >> 6;           // wave 0..7
    const int l    = t & 63;
    const int q    = l >> 4;
    const int ln   = l & 15;
    const int wr   = w >> 2;           // row-half (32 rows)
    const int wj   = w & 3;            // j-quarter of the 128-j tile (32 j)

    const int jts    = (h == 1 && rblk < 8) ? 1 : 0;
    const int Usteps = (2 - jts) * 32;     // 4 jtiles x 8 kc per jt

    // prologue: stages 0..2 (drained by the Phase-A __syncthreads)
    stage_b(MH, ML, sB, b, jts, 0, t);
    stage_b(MH, ML, sB, b, jts, 1, t);
    stage_b(MH, ML, sB, b, jts, 2, t);

    // ---------------- Phase A ----------------
    {
        const int wrA = w >> 2, wcA = w & 3;
        f32x4 accA[2][4];
        const f32x4 z4 = {0.f, 0.f, 0.f, 0.f};
#pragma unroll
        for (int i = 0; i < 2; ++i)
#pragma unroll
            for (int j2 = 0; j2 < 4; ++j2) accA[i][j2] = z4;

        for (int kc = 0; kc < 8; ++kc) {
            const int c0 = kc * 32;
            h16x8 aH[2], aL[2], bH[4], bL[4];
#pragma unroll
            for (int ti = 0; ti < 2; ++ti) {
                const size_t off =
                    (size_t)(b * 1024 + r0 + wrA * 32 + ti * 16 + ln) * 256 + c0 + q * 8;
                aH[ti] = *(const h16x8*)&MH[off];
                aL[ti] = *(const h16x8*)&ML[off];
            }
#pragma unroll
            for (int tj = 0; tj < 4; ++tj) {
                const size_t off =
                    (size_t)(h * 256 + wcA * 64 + tj * 16 + ln) * 256 + c0 + q * 8;
                bH[tj] = *(const h16x8*)&UHt[off];
                bL[tj] = *(const h16x8*)&ULt[off];
            }
#pragma unroll
            for (int ti = 0; ti < 2; ++ti)
#pragma unroll
                for (int tj = 0; tj < 4; ++tj)
                    accA[ti][tj] = __builtin_amdgcn_mfma_f32_16x16x32_f16(
                        aH[ti], bH[tj], accA[ti][tj], 0, 0, 0);
#pragma unroll
            for (int ti = 0; ti < 2; ++ti)
#pragma unroll
                for (int tj = 0; tj < 4; ++tj)
                    accA[ti][tj] = __builtin_amdgcn_mfma_f32_16x16x32_f16(
                        aL[ti], bH[tj], accA[ti][tj], 0, 0, 0);
#pragma unroll
            for (int ti = 0; ti < 2; ++ti)
#pragma unroll
                for (int tj = 0; tj < 4; ++tj)
                    accA[ti][tj] = __builtin_amdgcn_mfma_f32_16x16x32_f16(
                        aH[ti], bL[tj], accA[ti][tj], 0, 0, 0);
        }
#pragma unroll
        for (int ti = 0; ti < 2; ++ti)
#pragma unroll
            for (int tj = 0; tj < 4; ++tj)
#pragma unroll
                for (int reg = 0; reg < 4; ++reg) {
                    const int r = wrA * 32 + ti * 16 + q * 4 + reg;
                    const int d = wcA * 64 + tj * 16 + ln;
                    const float v = accA[ti][tj][reg];
                    const h16 hi = (h16)v;
                    const h16 lo = (h16)(v - (float)hi);
                    const int off = r * 256 + (((d >> 3) ^ (r & 7)) << 3) + (d & 7);
                    sP[0][off] = hi;
                    sP[1][off] = lo;
                }
    }
    __syncthreads();   // sP visible; prologue stages 0..2 drained

    // ---------------- Phase B: counted-vmcnt pipeline ----------------
    float gmin = INFINITY;
    float rm[2][4];
    f32x4 acc[2][2];
    const f32x4 z4 = {0.f, 0.f, 0.f, 0.f};

#pragma unroll 1
    for (int u = 0; u < Usteps; ++u) {
        const int kc = u & 7;
        const int jt = jts + (u >> 5);
        const bool dored = (rblk >= 8) || (jt == 1);

        if (u) {
            // allow only the newer in-flight stages; stage(u) forced retired
            if (u + 3 <= Usteps)      asm volatile("s_waitcnt vmcnt(4)" ::: "memory");
            else if (u + 2 <= Usteps) asm volatile("s_waitcnt vmcnt(2)" ::: "memory");
            else                      asm volatile("s_waitcnt vmcnt(0)" ::: "memory");
            asm volatile("s_waitcnt lgkmcnt(0)" ::: "memory");
            __builtin_amdgcn_s_barrier();
            __builtin_amdgcn_sched_barrier(0);
        }
        // issue next prefetch AFTER the barrier (its target buf was being
        // read until all waves passed the barrier above)
        if (u + 3 < Usteps) stage_b(MH, ML, sB, b, jts, u + 3, t);

        if (kc == 0) {
#pragma unroll
            for (int i = 0; i < 2; ++i)
#pragma unroll
                for (int j2 = 0; j2 < 2; ++j2) acc[i][j2] = z4;
            if ((u & 31) == 0) {
#pragma unroll
                for (int i = 0; i < 2; ++i)
#pragma unroll
                    for (int j2 = 0; j2 < 4; ++j2) rm[i][j2] = -INFINITY;
            }
        }

        h16x8 aH[2], aL[2], bH[2], bL[2];
#pragma unroll
        for (int ti = 0; ti < 2; ++ti) {
            const int r = wr * 32 + ti * 16 + ln;
            const int g = ((kc * 4 + q) ^ (r & 7)) * 8;
            aH[ti] = *(const h16x8*)&sP[0][r * 256 + g];
            aL[ti] = *(const h16x8*)&sP[1][r * 256 + g];
        }
        const h16* sBb = &sB[(size_t)(u & 3) * 8192];
#pragma unroll
        for (int tj = 0; tj < 2; ++tj) {
            const int jr = wj * 32 + tj * 16 + ln;
            const int cp = (q ^ ((jr >> 1) & 3)) * 8;   // T2 read swizzle
            bH[tj] = *(const h16x8*)&sBb[jr * 32 + cp];
            bL[tj] = *(const h16x8*)&sBb[4096 + jr * 32 + cp];
        }
#pragma unroll
        for (int tj = 0; tj < 2; ++tj)
#pragma unroll
            for (int ti = 0; ti < 2; ++ti)
                acc[ti][tj] = __builtin_amdgcn_mfma_f32_16x16x32_f16(
                    aH[ti], bH[tj], acc[ti][tj], 0, 0, 0);
#pragma unroll
        for (int tj = 0; tj < 2; ++tj)
#pragma unroll
            for (int ti = 0; ti < 2; ++ti)
                acc[ti][tj] = __builtin_amdgcn_mfma_f32_16x16x32_f16(
                    aL[ti], bH[tj], acc[ti][tj], 0, 0, 0);
#pragma unroll
        for (int tj = 0; tj < 2; ++tj)
#pragma unroll
            for (int ti = 0; ti < 2; ++ti)
                acc[ti][tj] = __builtin_amdgcn_mfma_f32_16x16x32_f16(
                    aH[ti], bL[tj], acc[ti][tj], 0, 0, 0);

        if (kc == 7) {
            if (dored) {
                const int jtile = (u >> 3) & 3;
#pragma unroll
                for (int ti = 0; ti < 2; ++ti)
#pragma unroll
                    for (int reg = 0; reg < 4; ++reg) {
                        float m = fmaxf(acc[ti][0][reg], acc[ti][1][reg]);
                        m = fmaxf(m, __shfl_xor(m, 1));
                        m = fmaxf(m, __shfl_xor(m, 2));
                        m = fmaxf(m, __shfl_xor(m, 4));
                        m = fmaxf(m, __shfl_xor(m, 8));
                        rm[ti][reg] = fmaxf(rm[ti][reg], m);
                    }
                if ((u & 31) == 31) {
#pragma unroll
                    for (int ti = 0; ti < 2; ++ti)
#pragma unroll
                        for (int reg = 0; reg < 4; ++reg)
                            if (ln == 0)
                                red[(jt * 8 + w) * 64 + wr * 32 + ti * 16 +
                                    q * 4 + reg] = rm[ti][reg];
                }
#pragma unroll
                for (int tj = 0; tj < 2; ++tj) {
                    float m = -INFINITY;
#pragma unroll
                    for (int ti = 0; ti < 2; ++ti)
#pragma unroll
                        for (int reg = 0; reg < 4; ++reg)
                            m = fmaxf(m, acc[ti][tj][reg]);
                    m = fmaxf(m, __shfl_xor(m, 16));
                    m = fmaxf(m, __shfl_xor(m, 32));
                    if (q == 0)
                        scm[wr][jtile * 128 + wj * 32 + tj * 16 + ln] = m;
                }
            }
            if (h == 0) {
#pragma unroll
                for (int ti = 0; ti < 2; ++ti)
#pragma unroll
                    for (int tj = 0; tj < 2; ++tj)
#pragma unroll
                        for (int reg = 0; reg < 4; ++reg)
                            gmin = fminf(gmin, acc[ti][tj][reg]);
            }
        }
        if ((u & 31) == 31) {
            // publish colmax for this jt (raw barrier: no vmcnt drain)
            asm volatile("s_waitcnt lgkmcnt(0)" ::: "memory");
            __builtin_amdgcn_s_barrier();
            if (dored)
                pcm[(size_t)(hb * 16 + rblk) * 1024 + jt * 512 + t] =
                    fmaxf(scm[0][t], scm[1][t]) * 0.015625f;
        }
    }

    // ---------------- epilogue ----------------
#pragma unroll
    for (int off = 1; off < 64; off <<= 1) gmin = fminf(gmin, __shfl_xor(gmin, off));
    if (l == 0) red[1024 + w] = gmin;
    __syncthreads();

    if (t < 64) {
        float hh = -INFINITY;
#pragma unroll
        for (int w2 = 0; w2 < 8; ++w2)
            hh = fmaxf(hh, red[(8 + w2) * 64 + t]);       // jt=1
        if (rblk < 8) {
            rmax_hi[(size_t)hb * 1024 + r0 + t] = hh * 0.015625f;
        } else {
            float a = hh;
#pragma unroll
            for (int w2 = 0; w2 < 8; ++w2)
                a = fmaxf(a, red[w2 * 64 + t]);           // jt=0
            rmax_all[(size_t)hb * 1024 + r0 + t] = a * 0.015625f;
        }
    }
    if (t == 0 && hb < 32) {
        float g4 = red[1024];
#pragma unroll
        for (int i = 1; i < 8; ++i) g4 = fminf(g4, red[1024 + i]);
        atomicMin(m0key, fkey(g4 * 0.015625f));
    }
}

// ---------------------------------------------------------------------------
// k_fin: fused alpha (activation post-reduction) + softmax + chunked pooling.
// ---------------------------------------------------------------------------
__global__ __launch_bounds__(256)
void k_fin(const float* __restrict__ rmax_all, const float* __restrict__ rmax_hi,
           const float* __restrict__ pcm, const int* __restrict__ m0key,
           const float* __restrict__ x1, const float* __restrict__ x2,
           float* __restrict__ out) {
    __shared__ float wv[512];
    __shared__ float sm[4], ss[4];
    const int blk   = blockIdx.x;
    const int chunk = blk & 1;
    const int seg   = (blk >> 1) & 1;
    const int hb    = blk >> 2;
    const int b     = hb & 31;
    const int t     = threadIdx.x;
    const float m0  = funkey(*m0key);

    float a2[2];
#pragma unroll
    for (int half = 0; half < 2; ++half) {
        const int i = seg * 512 + half * 256 + t;
        float rraw;
        if (seg == 0) rraw = fmaxf(m0, rmax_hi[(size_t)hb * 1024 + i]);
        else          rraw = rmax_all[(size_t)hb * 1024 + i];
        float call = -INFINITY, chi = -INFINITY;
#pragma unroll
        for (int rb = 0; rb < 16; ++rb) {
            const float v = pcm[(size_t)(hb * 16 + rb) * 1024 + i];
            call = fmaxf(call, v);
            if (rb >= 8) chi = fmaxf(chi, v);
        }
        const float craw = (seg == 0) ? fmaxf(m0, chi) : call;
        a2[half] = nonsat(rraw) + nonsat(craw);
    }
    const float a0 = a2[0], a1 = a2[1];

    float m = fmaxf(a0, a1);
#pragma unroll
    for (int off = 1; off < 64; off <<= 1) m = fmaxf(m, __shfl_xor(m, off));
    if ((t & 63) == 0) sm[t >> 6] = m;
    __syncthreads();
    const float amax = fmaxf(fmaxf(sm[0], sm[1]), fmaxf(sm[2], sm[3]));

    const float e0 = __expf(a0 - amax), e1 = __expf(a1 - amax);
    wv[t] = e0; wv[t + 256] = e1;
    float s = e0 + e1;
#pragma unroll
    for (int off = 1; off < 64; off <<= 1) s += __shfl_xor(s, off);
    if ((t & 63) == 0) ss[t >> 6] = s;
    __syncthreads();
    const float inv = 1.0f / (ss[0] + ss[1] + ss[2] + ss[3]);

    const int lo = chunk * 256;
    float acc = 0.0f;
    if (seg == 0) {
        const float* xp = x1 + ((size_t)b * 512 + lo) * 256 + t;
#pragma unroll 4
        for (int l = 0; l < 256; ++l)
            acc = fmaf(wv[lo + l], xp[(size_t)l * 256], acc);
        atomicAdd(&out[(hb * 2 + seg) * 256 + t], acc * inv);
    } else if (t < 192) {
        const float* xp = x2 + ((size_t)b * 512 + lo) * 192 + t;
#pragma unroll 4
        for (int l = 0; l < 256; ++l)
            acc = fmaf(wv[lo + l], xp[(size_t)l * 192], acc);
        atomicAdd(&out[(hb * 2 + seg) * 256 + t], acc * inv);
    }
}

extern "C" void kernel_launch(void* const* d_in, const int* in_sizes, int n_in,
                              void* d_out, int out_size, void* d_ws, size_t ws_size,
                              hipStream_t stream) {
    const float* x1 = (const float*)d_in[0];
    const float* x2 = (const float*)d_in[1];
    const float* U  = (const float*)d_in[2];
    float* out = (float*)d_out;
    char* wsb  = (char*)d_ws;

    h16*   MHp  = (h16*)(wsb + MH_OFF);
    h16*   MLp  = (h16*)(wsb + ML_OFF);
    h16*   UHt  = (h16*)(wsb + UHT_OFF);
    h16*   ULt  = (h16*)(wsb + ULT_OFF);
    float* rma  = (float*)(wsb + RMA_OFF);
    float* rmh  = (float*)(wsb + RMH_OFF);
    float* pcm  = (float*)(wsb + PCM_OFF);
    int*   m0k  = (int*)(wsb + M0_OFF);

    hipLaunchKernelGGL(k_prep, dim3(8448), dim3(256), 0, stream, x1, x2, U,
                       MHp, MLp, UHt, ULt, m0k, out);
    hipLaunchKernelGGL(k_main, dim3(1024), dim3(512), 0, stream, MHp, MLp,
                       UHt, ULt, rma, rmh, pcm, m0k);
    hipLaunchKernelGGL(k_fin,  dim3(256),  dim3(256), 0, stream, rma, rmh,
                       pcm, m0k, x1, x2, out);
}